// Round 6
// baseline (644.384 us; speedup 1.0000x reference)
//
#include <hip/hip_runtime.h>
#include <math.h>

#define NTOK   2048
#define D      512
#define NV     100000

typedef __attribute__((ext_vector_type(8)))  short bf16x8;
typedef __attribute__((ext_vector_type(16))) float f32x16;

// ---- strip geometry: 64 cols/block, one LDS pass ----
// seg strips: 157, 157, 469, 782  (bases 0, 157, 314, 783; total 1565)

// ---- workspace layout (bytes) ----
#define WS_FRAGS 0u           // 4 segs * 2048 * 512 * 2B = 8,388,608
#define WS_LISTS 8388608u     // 4 * 2048 * 4B = 32,768
#define WS_PART  8421376u     // 1565 * 2048 * 2B (bf16) = 6,410,240 (region 6,422,528)
#define WS_CUR   14843904u    // 16
#define WS_PAD   14843920u    // 16
#define WS_CL    14843936u    // 2048*3*4 = 24,576
#define WS_TGT   14868512u    // 2048*4   = 8,192
#define WS_ACC   14876704u    // 4*2049*4 = 32,784  (end 14,909,488)

__device__ __forceinline__ int cluster_of(int t){
  return (t < 10000) ? 0 : (t < 20000) ? 1 : (t < 50000) ? 2 : 3;
}
__device__ __forceinline__ bool is_root(int c){
  return c==5 || c==17 || c==123 || c==10005 || c==20007 || c==50011;
}
// f32 -> bf16 round-to-nearest-even
__device__ __forceinline__ unsigned short f2bf(float f){
  unsigned int u = __float_as_uint(f);
  u += 0x7fffu + ((u >> 16) & 1u);
  return (unsigned short)(u >> 16);
}
__device__ __forceinline__ float bf2f(unsigned short u){
  unsigned int v = ((unsigned int)u) << 16;
  return __uint_as_float(v);
}

// ---------------------------------------------------------------------------
// K1: per-token cluster logits (3 dots) + exact-f32 target logit. 1 wave/token.
// ---------------------------------------------------------------------------
__global__ void k_token_logits(const float* __restrict__ hidden,
                               const float* __restrict__ weight,
                               const float* __restrict__ bias,
                               const float* __restrict__ cw,
                               const float* __restrict__ cb,
                               const int*   __restrict__ target,
                               float* __restrict__ cl_out,   // [2048][3]
                               float* __restrict__ tgt_out)  // [2048]
{
  int wave = threadIdx.x >> 6;
  int lane = threadIdx.x & 63;
  int n = blockIdx.x * 4 + wave;
  if (n >= NTOK) return;
  const float* h = hidden + (size_t)n * D + lane * 8;
  int t = target[n];
  const float* wt = weight + (size_t)t * D + lane * 8;
  float hv[8];
  #pragma unroll
  for (int i = 0; i < 8; ++i) hv[i] = h[i];
  float acc[4] = {0.f, 0.f, 0.f, 0.f};
  #pragma unroll
  for (int j = 0; j < 3; ++j){
    const float* cwj = cw + j * D + lane * 8;
    float s = 0.f;
    #pragma unroll
    for (int i = 0; i < 8; ++i) s += hv[i] * cwj[i];
    acc[j] = s;
  }
  {
    float s = 0.f;
    #pragma unroll
    for (int i = 0; i < 8; ++i) s += hv[i] * wt[i];
    acc[3] = s;
  }
  #pragma unroll
  for (int m = 1; m < 64; m <<= 1){
    #pragma unroll
    for (int j = 0; j < 4; ++j) acc[j] += __shfl_xor(acc[j], m, 64);
  }
  if (lane == 0){
    cl_out[n*3+0] = acc[0] + cb[0];
    cl_out[n*3+1] = acc[1] + cb[1];
    cl_out[n*3+2] = acc[2] + cb[2];
    float tg = acc[3] + bias[t];
    if (is_root(t)) tg = -INFINITY;
    tgt_out[n] = tg;
  }
}

// ---------------------------------------------------------------------------
// K2: build per-segment token lists. seg0 = identity; tails via atomic cursor.
// ---------------------------------------------------------------------------
__global__ void k_build_lists(const int* __restrict__ target,
                              int* __restrict__ lists, int* __restrict__ cursors)
{
  int n = blockIdx.x * blockDim.x + threadIdx.x;
  if (n >= NTOK) return;
  lists[n] = n;  // seg 0 identity
  int c = cluster_of(target[n]);
  if (c > 0){
    int pos = atomicAdd(cursors + c, 1);
    lists[c * 2048 + pos] = n;
  }
}

// ---------------------------------------------------------------------------
// K3: pad lists to multiples of 256 with sentinel token (=NTOK), write counts.
// ---------------------------------------------------------------------------
__global__ void k_pad_lists(int* __restrict__ lists, const int* __restrict__ cursors,
                            int* __restrict__ padded)
{
  if (threadIdx.x == 0) padded[0] = NTOK;
  for (int s = 1; s < 4; ++s){
    int c = cursors[s];
    int p = (c + 255) & ~255;
    if (threadIdx.x == 0) padded[s] = p;
    for (int i = c + threadIdx.x; i < p; i += blockDim.x)
      lists[s * 2048 + i] = NTOK;
  }
}

// ---------------------------------------------------------------------------
// K4: build bf16 A-fragments in MFMA-native layout per segment.
// elem offset = ((mf*32 + ks)*64 + lane)*8 ; row = mf*32+(lane&31),
// k = ks*16 + (lane>>5)*8 + j  (same k-convention as B).
// ---------------------------------------------------------------------------
__global__ void k_build_frags(const float* __restrict__ hidden,
                              const int*   __restrict__ lists,
                              const int*   __restrict__ padded,
                              unsigned short* __restrict__ frags)
{
  int tg   = blockIdx.x * 256 + threadIdx.x;   // [0, 4*131072)
  int seg  = tg >> 17;
  int s    = tg & 131071;
  int lane = s & 63;
  int ks   = (s >> 6) & 31;
  int mf   = s >> 11;
  int row  = mf * 32 + (lane & 31);
  if (row >= padded[seg]) return;
  int token = lists[seg * 2048 + row];
  unsigned int w[4];
  if (token < NTOK){
    const float* h = hidden + (size_t)token * D + ks * 16 + (lane >> 5) * 8;
    #pragma unroll
    for (int i = 0; i < 4; ++i){
      unsigned short lo = f2bf(h[2*i]);
      unsigned short hi = f2bf(h[2*i+1]);
      w[i] = (unsigned int)lo | ((unsigned int)hi << 16);
    }
  } else {
    w[0] = w[1] = w[2] = w[3] = 0u;
  }
  size_t off = ((size_t)seg * 2048 * 512) + (((size_t)(mf * 32 + ks)) * 64 + lane) * 8;
  uint4 val; val.x = w[0]; val.y = w[1]; val.z = w[2]; val.w = w[3];
  *(uint4*)(frags + off) = val;
}

// ---------------------------------------------------------------------------
// K5: Σexp GEMM. 64-col strips, 512 threads (8 waves = 4 row-waves x 2
// col-waves), one B pass per block (Bs 64 KB frag-native, 0-conflict layout).
// Epilogue: in-register halving-tree reduce (no LDS scratch), rows -> racc
// (per-col-wave copy, race-free). Store once as bf16 partials, no atomics.
// ---------------------------------------------------------------------------
__device__ __forceinline__ void epi_shfl(const f32x16& a, float b0v, int r0,
                                         int lane, float* __restrict__ raccw)
{
  float v[16];
  #pragma unroll
  for (int r = 0; r < 16; ++r) v[r] = __expf(a[r] + b0v);
  // halving tree over 16 lanes: level m: bit=0 lanes keep low regs, bit=1 high
  #pragma unroll
  for (int lvl = 0; lvl < 4; ++lvl){
    int m = 1 << lvl;
    int half = 8 >> lvl;
    bool up = (lane & m) != 0;
    #pragma unroll
    for (int i = 0; i < half; ++i){
      float lo = v[i], hi_ = v[i + half];
      float other = __shfl_xor(up ? lo : hi_, m, 64);
      v[i] = (up ? hi_ : lo) + other;
    }
  }
  float s = v[0] + __shfl_xor(v[0], 16, 64);   // combine the two 16-lane halves
  if ((lane & 16) == 0){
    int l  = lane & 15;
    int rl = ((l & 1) << 3) | ((l & 2) << 1) | ((l & 4) >> 1) | ((l & 8) >> 3);
    int row = (rl & 3) + 8 * (rl >> 2) + 4 * (lane >> 5);  // verified C/D layout
    raccw[r0 + row] += s;   // 32 active lanes, 32 distinct rows: conflict-free
  }
}

__global__ __launch_bounds__(512, 4)
void k_gemm(const unsigned short* __restrict__ frags,
            const float* __restrict__ weight,
            const float* __restrict__ bias,
            const int*   __restrict__ padded,
            unsigned short* __restrict__ partials)   // [1565][2048] bf16
{
  __shared__ unsigned short Bs[512 * 64];      // 64 KB
  __shared__ float racc[2][2048];              // 16 KB (per col-wave)

  int bid = blockIdx.x;
  int seg, strip0, colstart, colend;
  if      (bid < 157) { seg = 0; strip0 = 0;    colstart = 0;     colend = 10000;  }
  else if (bid < 314) { seg = 1; strip0 = 157;  colstart = 10000; colend = 20000;  }
  else if (bid < 783) { seg = 2; strip0 = 314;  colstart = 20000; colend = 50000;  }
  else                { seg = 3; strip0 = 783;  colstart = 50000; colend = 100000; }
  int col_base = colstart + (bid - strip0) * 64;

  int tid   = threadIdx.x;
  int wave  = tid >> 6;          // 0..7
  int wr    = wave >> 1;         // row-wave 0..3
  int wc    = wave & 1;          // col-wave 0..1
  int lane  = tid & 63;
  int laneM = lane & 31;
  int hi    = lane >> 5;
  int M = padded[seg];
  const unsigned short* fseg = frags + (size_t)seg * 2048 * 512;

  // zero both racc copies
  for (int r = tid; r < 4096; r += 512) ((float*)racc)[r] = 0.f;

  // ---- load B strip: 64 cols x 512 k, f32 -> bf16, frag-native LDS ----
  for (int it = 0; it < 16; ++it){
    int id  = it * 512 + tid;               // [0, 8192)
    int col = id >> 7;                      // 0..63
    int k0  = (id & 127) * 4;               // 0..508
    int cg  = col_base + col;
    float4 v = make_float4(0.f, 0.f, 0.f, 0.f);
    if (cg < colend) v = *(const float4*)(weight + (size_t)cg * D + k0);
    unsigned int lo  = (unsigned int)f2bf(v.x) | ((unsigned int)f2bf(v.y) << 16);
    unsigned int hi2 = (unsigned int)f2bf(v.z) | ((unsigned int)f2bf(v.w) << 16);
    int ks = k0 >> 4, bhi = (k0 >> 3) & 1, j0 = k0 & 7;
    int off = ks * 2048 + (col >> 5) * 1024 + bhi * 512 + (col & 31) * 16 + j0 * 2;
    off ^= ((ks & 3) << 5) ^ (bhi << 4);
    uint2 pk; pk.x = lo; pk.y = hi2;
    *(uint2*)((char*)Bs + off) = pk;
  }
  __syncthreads();   // B ready, racc zeroed

  int cg0 = col_base + wc * 32 + laneM;
  float b0v = (cg0 < colend && !is_root(cg0)) ? bias[cg0] : -INFINITY;

  const char* bsc = (const char*)Bs;
  int roff = wc * 1024 + ((lane * 16) ^ (hi << 4));

  for (int m0 = 0; m0 < M; m0 += 256){
    int r0 = m0 + wr * 64;
    f32x16 acc0, acc1;
    #pragma unroll
    for (int i = 0; i < 16; ++i){ acc0[i] = 0.f; acc1[i] = 0.f; }

    const unsigned short* pa0 = fseg + (size_t)(r0 >> 5) * 16384 + (size_t)lane * 8;
    const unsigned short* pa1 = pa0 + 16384;

    #pragma unroll
    for (int ks = 0; ks < 32; ++ks){
      bf16x8 a0 = *(const bf16x8*)(pa0 + ks * 512);
      bf16x8 a1 = *(const bf16x8*)(pa1 + ks * 512);
      bf16x8 b0 = *(const bf16x8*)(bsc + (ks * 2048 + (roff ^ ((ks & 3) << 5))));
      acc0 = __builtin_amdgcn_mfma_f32_32x32x16_bf16(a0, b0, acc0, 0, 0, 0);
      acc1 = __builtin_amdgcn_mfma_f32_32x32x16_bf16(a1, b0, acc1, 0, 0, 0);
    }
    epi_shfl(acc0, b0v, r0,      lane, racc[wc]);
    epi_shfl(acc1, b0v, r0 + 32, lane, racc[wc]);
  }
  __syncthreads();   // all waves done accumulating

  // ---- store per-strip partial row sums (coalesced, non-atomic, bf16) ----
  for (int r = tid; r < M; r += 512)
    partials[(size_t)bid * 2048 + r] = f2bf(racc[0][r] + racc[1][r]);
}

// ---------------------------------------------------------------------------
// K5b: reduce bf16 partials over strips of each segment, scatter via lists.
// ---------------------------------------------------------------------------
__global__ void k_reduce(const unsigned short* __restrict__ partials,
                         const int*   __restrict__ lists,
                         const int*   __restrict__ padded,
                         float* __restrict__ acc_out)     // [4][2049]
{
  int b   = blockIdx.x;          // 32 blocks: seg = b>>3, row chunk = b&7
  int seg = b >> 3;
  int row = (b & 7) * 256 + threadIdx.x;
  if (row >= padded[seg]) return;
  int base, cnt;
  if      (seg == 0){ base = 0;   cnt = 157; }
  else if (seg == 1){ base = 157; cnt = 157; }
  else if (seg == 2){ base = 314; cnt = 469; }
  else              { base = 783; cnt = 782; }
  float s = 0.f;
  int j = 0;
  for (; j + 4 <= cnt; j += 4){
    s += bf2f(partials[(size_t)(base + j    ) * 2048 + row]);
    s += bf2f(partials[(size_t)(base + j + 1) * 2048 + row]);
    s += bf2f(partials[(size_t)(base + j + 2) * 2048 + row]);
    s += bf2f(partials[(size_t)(base + j + 3) * 2048 + row]);
  }
  for (; j < cnt; ++j) s += bf2f(partials[(size_t)(base + j) * 2048 + row]);
  int token = lists[seg * 2048 + row];
  if (token < NTOK) acc_out[seg * 2049 + token] = s;
}

// ---------------------------------------------------------------------------
// K6: finalize NLL per token.
// ---------------------------------------------------------------------------
__global__ void k_finalize(const float* __restrict__ accs,   // [4][2049]
                           const float* __restrict__ cl,     // [2048][3]
                           const float* __restrict__ tgt,
                           const int*   __restrict__ target,
                           float* __restrict__ out)
{
  int n = blockIdx.x * blockDim.x + threadIdx.x;
  if (n >= NTOK) return;
  int c = cluster_of(target[n]);
  float e0 = __expf(cl[n*3+0]), e1 = __expf(cl[n*3+1]), e2 = __expf(cl[n*3+2]);
  float head_lse = __logf(accs[n] + e0 + e1 + e2);
  float nll;
  if (c == 0){
    nll = head_lse - tgt[n];
  } else {
    float tail_lse = __logf(accs[c * 2049 + n]);
    nll = head_lse + tail_lse - cl[n*3 + (3 - c)] - tgt[n];
  }
  out[n] = nll;
}

extern "C" void kernel_launch(void* const* d_in, const int* in_sizes, int n_in,
                              void* d_out, int out_size, void* d_ws, size_t ws_size,
                              hipStream_t stream)
{
  (void)in_sizes; (void)n_in; (void)out_size; (void)ws_size;
  const float* hidden = (const float*)d_in[0];
  const float* weight = (const float*)d_in[1];
  const float* bias   = (const float*)d_in[2];
  const float* cw     = (const float*)d_in[3];
  const float* cb     = (const float*)d_in[4];
  const int*   target = (const int*)d_in[5];
  float* out = (float*)d_out;
  char*  ws  = (char*)d_ws;

  unsigned short* frags    = (unsigned short*)(ws + WS_FRAGS);
  int*   lists    = (int*)(ws + WS_LISTS);
  unsigned short* partials = (unsigned short*)(ws + WS_PART);
  int*   cursors  = (int*)(ws + WS_CUR);
  int*   padded   = (int*)(ws + WS_PAD);
  float* cl       = (float*)(ws + WS_CL);
  float* tgt      = (float*)(ws + WS_TGT);
  float* acc      = (float*)(ws + WS_ACC);

  hipMemsetAsync(ws + WS_CUR, 0, 16, stream);   // cursors only

  k_token_logits<<<512, 256, 0, stream>>>(hidden, weight, bias, cw, cb, target, cl, tgt);
  k_build_lists <<<8,   256, 0, stream>>>(target, lists, cursors);
  k_pad_lists   <<<1,   256, 0, stream>>>(lists, cursors, padded);
  k_build_frags <<<2048,256, 0, stream>>>(hidden, lists, padded, frags);
  k_gemm        <<<1565,512, 0, stream>>>(frags, weight, bias, padded, partials);
  k_reduce      <<<32,  256, 0, stream>>>(partials, lists, padded, acc);
  k_finalize    <<<8,   256, 0, stream>>>(acc, cl, tgt, target, out);
}

// Round 8
// 511.818 us; speedup vs baseline: 1.2590x; 1.2590x over previous
//
#include <hip/hip_runtime.h>
#include <math.h>

#define NTOK   2048
#define D      512
#define NV     100000

typedef __attribute__((ext_vector_type(8)))  short bf16x8;
typedef __attribute__((ext_vector_type(16))) float f32x16;

// ---- strip geometry: 64 cols/block, 2x 32-col LDS chunks ----
// seg strips: 157, 157, 469, 782  (bases 0, 157, 314, 783; total 1565)

// ---- workspace layout (bytes) ----
#define WS_FRAGS 0u           // 4 segs * 2048 * 512 * 2B = 8,388,608
#define WS_LISTS 8388608u     // 4 * 2048 * 4B = 32,768
#define WS_PART  8421376u     // 1565 * 2048 * 2B (bf16) = 6,410,240 (region 6,422,528)
#define WS_CUR   14843904u    // 16
#define WS_PAD   14843920u    // 16
#define WS_CL    14843936u    // 2048*3*4 = 24,576
#define WS_TGT   14868512u    // 2048*4   = 8,192
#define WS_ACC   14876704u    // 4*2049*4 = 32,784  (end 14,909,488)

__device__ __forceinline__ int cluster_of(int t){
  return (t < 10000) ? 0 : (t < 20000) ? 1 : (t < 50000) ? 2 : 3;
}
__device__ __forceinline__ bool is_root(int c){
  return c==5 || c==17 || c==123 || c==10005 || c==20007 || c==50011;
}
// f32 -> bf16 round-to-nearest-even
__device__ __forceinline__ unsigned short f2bf(float f){
  unsigned int u = __float_as_uint(f);
  u += 0x7fffu + ((u >> 16) & 1u);
  return (unsigned short)(u >> 16);
}
__device__ __forceinline__ float bf2f(unsigned short u){
  unsigned int v = ((unsigned int)u) << 16;
  return __uint_as_float(v);
}

// ---------------------------------------------------------------------------
// K1: per-token cluster logits (3 dots) + exact-f32 target logit. 1 wave/token.
// ---------------------------------------------------------------------------
__global__ void k_token_logits(const float* __restrict__ hidden,
                               const float* __restrict__ weight,
                               const float* __restrict__ bias,
                               const float* __restrict__ cw,
                               const float* __restrict__ cb,
                               const int*   __restrict__ target,
                               float* __restrict__ cl_out,   // [2048][3]
                               float* __restrict__ tgt_out)  // [2048]
{
  int wave = threadIdx.x >> 6;
  int lane = threadIdx.x & 63;
  int n = blockIdx.x * 4 + wave;
  if (n >= NTOK) return;
  const float* h = hidden + (size_t)n * D + lane * 8;
  int t = target[n];
  const float* wt = weight + (size_t)t * D + lane * 8;
  float hv[8];
  #pragma unroll
  for (int i = 0; i < 8; ++i) hv[i] = h[i];
  float acc[4] = {0.f, 0.f, 0.f, 0.f};
  #pragma unroll
  for (int j = 0; j < 3; ++j){
    const float* cwj = cw + j * D + lane * 8;
    float s = 0.f;
    #pragma unroll
    for (int i = 0; i < 8; ++i) s += hv[i] * cwj[i];
    acc[j] = s;
  }
  {
    float s = 0.f;
    #pragma unroll
    for (int i = 0; i < 8; ++i) s += hv[i] * wt[i];
    acc[3] = s;
  }
  #pragma unroll
  for (int m = 1; m < 64; m <<= 1){
    #pragma unroll
    for (int j = 0; j < 4; ++j) acc[j] += __shfl_xor(acc[j], m, 64);
  }
  if (lane == 0){
    cl_out[n*3+0] = acc[0] + cb[0];
    cl_out[n*3+1] = acc[1] + cb[1];
    cl_out[n*3+2] = acc[2] + cb[2];
    float tg = acc[3] + bias[t];
    if (is_root(t)) tg = -INFINITY;
    tgt_out[n] = tg;
  }
}

// ---------------------------------------------------------------------------
// K2: build per-segment token lists. seg0 = identity; tails via atomic cursor.
// ---------------------------------------------------------------------------
__global__ void k_build_lists(const int* __restrict__ target,
                              int* __restrict__ lists, int* __restrict__ cursors)
{
  int n = blockIdx.x * blockDim.x + threadIdx.x;
  if (n >= NTOK) return;
  lists[n] = n;  // seg 0 identity
  int c = cluster_of(target[n]);
  if (c > 0){
    int pos = atomicAdd(cursors + c, 1);
    lists[c * 2048 + pos] = n;
  }
}

// ---------------------------------------------------------------------------
// K3: pad lists to multiples of 256 with sentinel token (=NTOK), write counts.
// ---------------------------------------------------------------------------
__global__ void k_pad_lists(int* __restrict__ lists, const int* __restrict__ cursors,
                            int* __restrict__ padded)
{
  if (threadIdx.x == 0) padded[0] = NTOK;
  for (int s = 1; s < 4; ++s){
    int c = cursors[s];
    int p = (c + 255) & ~255;
    if (threadIdx.x == 0) padded[s] = p;
    for (int i = c + threadIdx.x; i < p; i += blockDim.x)
      lists[s * 2048 + i] = NTOK;
  }
}

// ---------------------------------------------------------------------------
// K4: build bf16 A-fragments in MFMA-native layout per segment.
// elem offset = ((mf*32 + ks)*64 + lane)*8 ; row = mf*32+(lane&31),
// k = ks*16 + (lane>>5)*8 + j  (same k-convention as B).
// ---------------------------------------------------------------------------
__global__ void k_build_frags(const float* __restrict__ hidden,
                              const int*   __restrict__ lists,
                              const int*   __restrict__ padded,
                              unsigned short* __restrict__ frags)
{
  int tg   = blockIdx.x * 256 + threadIdx.x;   // [0, 4*131072)
  int seg  = tg >> 17;
  int s    = tg & 131071;
  int lane = s & 63;
  int ks   = (s >> 6) & 31;
  int mf   = s >> 11;
  int row  = mf * 32 + (lane & 31);
  if (row >= padded[seg]) return;
  int token = lists[seg * 2048 + row];
  unsigned int w[4];
  if (token < NTOK){
    const float* h = hidden + (size_t)token * D + ks * 16 + (lane >> 5) * 8;
    #pragma unroll
    for (int i = 0; i < 4; ++i){
      unsigned short lo = f2bf(h[2*i]);
      unsigned short hi = f2bf(h[2*i+1]);
      w[i] = (unsigned int)lo | ((unsigned int)hi << 16);
    }
  } else {
    w[0] = w[1] = w[2] = w[3] = 0u;
  }
  size_t off = ((size_t)seg * 2048 * 512) + (((size_t)(mf * 32 + ks)) * 64 + lane) * 8;
  uint4 val; val.x = w[0]; val.y = w[1]; val.z = w[2]; val.w = w[3];
  *(uint4*)(frags + off) = val;
}

// ---------------------------------------------------------------------------
// K5: Σexp GEMM. 64-col strips (2 x 32-col chunks), 256 threads, 3 blocks/CU
// (LDS 49 KB). K-loop identical to round-5 (proven VGPR=116, no spill).
// Epilogue: round-5 f32 stride-36 transpose-reduce idiom, half-height:
// two 16x36 f32 passes per acc; f32 racc += (wave-owned rows).
// ---------------------------------------------------------------------------
__device__ __forceinline__ void epi(const f32x16& a, float b0v, int r0,
                                    int lane, float* __restrict__ sc_w,
                                    float* __restrict__ racc)
{
  int hi    = lane >> 5;
  int laneM = lane & 31;
  #pragma unroll
  for (int p = 0; p < 2; ++p){
    // write: 8 regs -> 16 rows x 32 cols f32, stride 36 (conflict-free)
    #pragma unroll
    for (int r = 0; r < 8; ++r){
      int row = (r & 3) + 8 * (r >> 2) + 4 * hi;          // 0..15 (local)
      sc_w[row * 36 + laneM] = __expf(a[p * 8 + r] + b0v);
    }
    // read: lane -> row (lane&15), col-quarter (lane>>4); 2x float4
    int rho = lane & 15;
    int q   = lane >> 4;                                  // 0..3
    const float* pr = sc_w + rho * 36 + q * 8;
    float4 v0 = *(const float4*)(pr);
    float4 v1 = *(const float4*)(pr + 4);
    float s = ((v0.x + v0.y) + (v0.z + v0.w)) + ((v1.x + v1.y) + (v1.z + v1.w));
    s += __shfl_xor(s, 16, 64);
    s += __shfl_xor(s, 32, 64);
    if (lane < 16)
      racc[r0 + p * 16 + rho] += s;                       // wave-owned rows
  }
}

__global__ __launch_bounds__(256, 3)
void k_gemm(const unsigned short* __restrict__ frags,
            const float* __restrict__ weight,
            const float* __restrict__ bias,
            const int*   __restrict__ padded,
            unsigned short* __restrict__ partials)   // [1565][2048] bf16
{
  __shared__ unsigned short Bs[512 * 32];      // 32 KB
  __shared__ float sc[4][16 * 36];             // 9 KB (per-wave 16x36 f32)
  __shared__ float racc[2048];                 // 8 KB f32 row accumulator

  int bid = blockIdx.x;
  int seg, strip0, colstart, colend;
  if      (bid < 157) { seg = 0; strip0 = 0;    colstart = 0;     colend = 10000;  }
  else if (bid < 314) { seg = 1; strip0 = 157;  colstart = 10000; colend = 20000;  }
  else if (bid < 783) { seg = 2; strip0 = 314;  colstart = 20000; colend = 50000;  }
  else                { seg = 3; strip0 = 783;  colstart = 50000; colend = 100000; }
  int col_base = colstart + (bid - strip0) * 64;

  int tid   = threadIdx.x;
  int wave  = tid >> 6;
  int lane  = tid & 63;
  int laneM = lane & 31;
  int hi    = lane >> 5;
  int M = padded[seg];
  const unsigned short* fseg = frags + (size_t)seg * 2048 * 512;
  float* sc_w = sc[wave];

  for (int r = tid; r < 2048; r += 256) racc[r] = 0.f;

  const char* bsc = (const char*)Bs;
  int roff = (lane * 16) ^ (hi << 4);   // B read base; (ks&3)<<5 XOR per iter

  for (int chunk = 0; chunk < 2; ++chunk){
    int cb = col_base + chunk * 32;
    // ---- load B chunk: 32 cols x 512 k, f32 -> bf16, frag-native LDS ----
    for (int it = 0; it < 16; ++it){
      int id  = it * 256 + tid;               // [0, 4096)
      int col = id >> 7;                      // 0..31
      int k0  = (id & 127) * 4;               // 0..508
      int cg  = cb + col;
      float4 v = make_float4(0.f, 0.f, 0.f, 0.f);
      if (cg < colend) v = *(const float4*)(weight + (size_t)cg * D + k0);
      unsigned int lo  = (unsigned int)f2bf(v.x) | ((unsigned int)f2bf(v.y) << 16);
      unsigned int hi2 = (unsigned int)f2bf(v.z) | ((unsigned int)f2bf(v.w) << 16);
      int ks = k0 >> 4, bhi = (k0 >> 3) & 1, j0 = k0 & 7;
      int off = ks * 1024 + bhi * 512 + col * 16 + j0 * 2;
      off ^= ((ks & 3) << 5) ^ (bhi << 4);
      uint2 pk; pk.x = lo; pk.y = hi2;
      *(uint2*)((char*)Bs + off) = pk;
    }
    __syncthreads();   // B ready (first pass: racc also zeroed)

    int cg0 = cb + laneM;
    float b0v = (cg0 < colend && !is_root(cg0)) ? bias[cg0] : -INFINITY;

    for (int m0 = 0; m0 < M; m0 += 256){
      int r0 = m0 + wave * 64;
      f32x16 acc0, acc1;
      #pragma unroll
      for (int i = 0; i < 16; ++i){ acc0[i] = 0.f; acc1[i] = 0.f; }

      const unsigned short* pa0 = fseg + (size_t)(r0 >> 5) * 16384 + (size_t)lane * 8;
      const unsigned short* pa1 = pa0 + 16384;

      #pragma unroll
      for (int ks = 0; ks < 32; ++ks){
        bf16x8 a0 = *(const bf16x8*)(pa0 + ks * 512);
        bf16x8 a1 = *(const bf16x8*)(pa1 + ks * 512);
        bf16x8 b0 = *(const bf16x8*)(bsc + (ks * 1024 + (roff ^ ((ks & 3) << 5))));
        acc0 = __builtin_amdgcn_mfma_f32_32x32x16_bf16(a0, b0, acc0, 0, 0, 0);
        acc1 = __builtin_amdgcn_mfma_f32_32x32x16_bf16(a1, b0, acc1, 0, 0, 0);
      }
      epi(acc0, b0v, r0,      lane, sc_w, racc);
      epi(acc1, b0v, r0 + 32, lane, sc_w, racc);
    }
    __syncthreads();   // all waves done with Bs before next chunk overwrites
  }

  // ---- store per-strip partial row sums (coalesced, non-atomic, bf16) ----
  for (int r = tid; r < M; r += 256)
    partials[(size_t)bid * 2048 + r] = f2bf(racc[r]);
}

// ---------------------------------------------------------------------------
// K5b: reduce bf16 partials over strips of each segment, scatter via lists.
// ---------------------------------------------------------------------------
__global__ void k_reduce(const unsigned short* __restrict__ partials,
                         const int*   __restrict__ lists,
                         const int*   __restrict__ padded,
                         float* __restrict__ acc_out)     // [4][2049]
{
  int b   = blockIdx.x;          // 32 blocks: seg = b>>3, row chunk = b&7
  int seg = b >> 3;
  int row = (b & 7) * 256 + threadIdx.x;
  if (row >= padded[seg]) return;
  int base, cnt;
  if      (seg == 0){ base = 0;   cnt = 157; }
  else if (seg == 1){ base = 157; cnt = 157; }
  else if (seg == 2){ base = 314; cnt = 469; }
  else              { base = 783; cnt = 782; }
  float s = 0.f;
  int j = 0;
  for (; j + 4 <= cnt; j += 4){
    s += bf2f(partials[(size_t)(base + j    ) * 2048 + row]);
    s += bf2f(partials[(size_t)(base + j + 1) * 2048 + row]);
    s += bf2f(partials[(size_t)(base + j + 2) * 2048 + row]);
    s += bf2f(partials[(size_t)(base + j + 3) * 2048 + row]);
  }
  for (; j < cnt; ++j) s += bf2f(partials[(size_t)(base + j) * 2048 + row]);
  int token = lists[seg * 2048 + row];
  if (token < NTOK) acc_out[seg * 2049 + token] = s;
}

// ---------------------------------------------------------------------------
// K6: finalize NLL per token.
// ---------------------------------------------------------------------------
__global__ void k_finalize(const float* __restrict__ accs,   // [4][2049]
                           const float* __restrict__ cl,     // [2048][3]
                           const float* __restrict__ tgt,
                           const int*   __restrict__ target,
                           float* __restrict__ out)
{
  int n = blockIdx.x * blockDim.x + threadIdx.x;
  if (n >= NTOK) return;
  int c = cluster_of(target[n]);
  float e0 = __expf(cl[n*3+0]), e1 = __expf(cl[n*3+1]), e2 = __expf(cl[n*3+2]);
  float head_lse = __logf(accs[n] + e0 + e1 + e2);
  float nll;
  if (c == 0){
    nll = head_lse - tgt[n];
  } else {
    float tail_lse = __logf(accs[c * 2049 + n]);
    nll = head_lse + tail_lse - cl[n*3 + (3 - c)] - tgt[n];
  }
  out[n] = nll;
}

extern "C" void kernel_launch(void* const* d_in, const int* in_sizes, int n_in,
                              void* d_out, int out_size, void* d_ws, size_t ws_size,
                              hipStream_t stream)
{
  (void)in_sizes; (void)n_in; (void)out_size; (void)ws_size;
  const float* hidden = (const float*)d_in[0];
  const float* weight = (const float*)d_in[1];
  const float* bias   = (const float*)d_in[2];
  const float* cw     = (const float*)d_in[3];
  const float* cb     = (const float*)d_in[4];
  const int*   target = (const int*)d_in[5];
  float* out = (float*)d_out;
  char*  ws  = (char*)d_ws;

  unsigned short* frags    = (unsigned short*)(ws + WS_FRAGS);
  int*   lists    = (int*)(ws + WS_LISTS);
  unsigned short* partials = (unsigned short*)(ws + WS_PART);
  int*   cursors  = (int*)(ws + WS_CUR);
  int*   padded   = (int*)(ws + WS_PAD);
  float* cl       = (float*)(ws + WS_CL);
  float* tgt      = (float*)(ws + WS_TGT);
  float* acc      = (float*)(ws + WS_ACC);

  hipMemsetAsync(ws + WS_CUR, 0, 16, stream);   // cursors only

  k_token_logits<<<512, 256, 0, stream>>>(hidden, weight, bias, cw, cb, target, cl, tgt);
  k_build_lists <<<8,   256, 0, stream>>>(target, lists, cursors);
  k_pad_lists   <<<1,   256, 0, stream>>>(lists, cursors, padded);
  k_build_frags <<<2048,256, 0, stream>>>(hidden, lists, padded, frags);
  k_gemm        <<<1565,256, 0, stream>>>(frags, weight, bias, padded, partials);
  k_reduce      <<<32,  256, 0, stream>>>(partials, lists, padded, acc);
  k_finalize    <<<8,   256, 0, stream>>>(acc, cl, tgt, target, out);
}

// Round 9
// 317.393 us; speedup vs baseline: 2.0302x; 1.6126x over previous
//
#include <hip/hip_runtime.h>
#include <math.h>

#define NTOK   2048
#define D      512
#define NV     100000

typedef __attribute__((ext_vector_type(8)))  short bf16x8;
typedef __attribute__((ext_vector_type(16))) float f32x16;

// ---- strip geometry: 64 cols/block, 2x 32-col LDS chunks ----
// seg strips: 157, 157, 469, 782  (bases 0, 157, 314, 783; total 1565)

// ---- workspace layout (bytes) ----
#define WS_FRAGS 0u           // 4 segs * 2048 * 512 * 2B = 8,388,608
#define WS_LISTS 8388608u     // 4 * 2048 * 4B = 32,768
#define WS_PART  8421376u     // 1565 * 2048 * 2B (bf16) = 6,410,240 (region 6,422,528)
#define WS_CUR   14843904u    // 16
#define WS_PAD   14843920u    // 16
#define WS_CL    14843936u    // 2048*3*4 = 24,576
#define WS_TGT   14868512u    // 2048*4   = 8,192
#define WS_ACC   14876704u    // 4*2049*4 = 32,784  (end 14,909,488)

__device__ __forceinline__ int cluster_of(int t){
  return (t < 10000) ? 0 : (t < 20000) ? 1 : (t < 50000) ? 2 : 3;
}
__device__ __forceinline__ bool is_root(int c){
  return c==5 || c==17 || c==123 || c==10005 || c==20007 || c==50011;
}
// f32 -> bf16 round-to-nearest-even
__device__ __forceinline__ unsigned short f2bf(float f){
  unsigned int u = __float_as_uint(f);
  u += 0x7fffu + ((u >> 16) & 1u);
  return (unsigned short)(u >> 16);
}
__device__ __forceinline__ float bf2f(unsigned short u){
  unsigned int v = ((unsigned int)u) << 16;
  return __uint_as_float(v);
}

// ---------------------------------------------------------------------------
// K1: per-token cluster logits (3 dots) + exact-f32 target logit. 1 wave/token.
// ---------------------------------------------------------------------------
__global__ void k_token_logits(const float* __restrict__ hidden,
                               const float* __restrict__ weight,
                               const float* __restrict__ bias,
                               const float* __restrict__ cw,
                               const float* __restrict__ cb,
                               const int*   __restrict__ target,
                               float* __restrict__ cl_out,   // [2048][3]
                               float* __restrict__ tgt_out)  // [2048]
{
  int wave = threadIdx.x >> 6;
  int lane = threadIdx.x & 63;
  int n = blockIdx.x * 4 + wave;
  if (n >= NTOK) return;
  const float* h = hidden + (size_t)n * D + lane * 8;
  int t = target[n];
  const float* wt = weight + (size_t)t * D + lane * 8;
  float hv[8];
  #pragma unroll
  for (int i = 0; i < 8; ++i) hv[i] = h[i];
  float acc[4] = {0.f, 0.f, 0.f, 0.f};
  #pragma unroll
  for (int j = 0; j < 3; ++j){
    const float* cwj = cw + j * D + lane * 8;
    float s = 0.f;
    #pragma unroll
    for (int i = 0; i < 8; ++i) s += hv[i] * cwj[i];
    acc[j] = s;
  }
  {
    float s = 0.f;
    #pragma unroll
    for (int i = 0; i < 8; ++i) s += hv[i] * wt[i];
    acc[3] = s;
  }
  #pragma unroll
  for (int m = 1; m < 64; m <<= 1){
    #pragma unroll
    for (int j = 0; j < 4; ++j) acc[j] += __shfl_xor(acc[j], m, 64);
  }
  if (lane == 0){
    cl_out[n*3+0] = acc[0] + cb[0];
    cl_out[n*3+1] = acc[1] + cb[1];
    cl_out[n*3+2] = acc[2] + cb[2];
    float tg = acc[3] + bias[t];
    if (is_root(t)) tg = -INFINITY;
    tgt_out[n] = tg;
  }
}

// ---------------------------------------------------------------------------
// K2: build per-segment token lists. seg0 = identity; tails via atomic cursor.
// ---------------------------------------------------------------------------
__global__ void k_build_lists(const int* __restrict__ target,
                              int* __restrict__ lists, int* __restrict__ cursors)
{
  int n = blockIdx.x * blockDim.x + threadIdx.x;
  if (n >= NTOK) return;
  lists[n] = n;  // seg 0 identity
  int c = cluster_of(target[n]);
  if (c > 0){
    int pos = atomicAdd(cursors + c, 1);
    lists[c * 2048 + pos] = n;
  }
}

// ---------------------------------------------------------------------------
// K3: pad lists to multiples of 256 with sentinel token (=NTOK), write counts.
// ---------------------------------------------------------------------------
__global__ void k_pad_lists(int* __restrict__ lists, const int* __restrict__ cursors,
                            int* __restrict__ padded)
{
  if (threadIdx.x == 0) padded[0] = NTOK;
  for (int s = 1; s < 4; ++s){
    int c = cursors[s];
    int p = (c + 255) & ~255;
    if (threadIdx.x == 0) padded[s] = p;
    for (int i = c + threadIdx.x; i < p; i += blockDim.x)
      lists[s * 2048 + i] = NTOK;
  }
}

// ---------------------------------------------------------------------------
// K4: build bf16 A-fragments in MFMA-native layout per segment.
// elem offset = ((mf*32 + ks)*64 + lane)*8 ; row = mf*32+(lane&31),
// k = ks*16 + (lane>>5)*8 + j  (same k-convention as B).
// ---------------------------------------------------------------------------
__global__ void k_build_frags(const float* __restrict__ hidden,
                              const int*   __restrict__ lists,
                              const int*   __restrict__ padded,
                              unsigned short* __restrict__ frags)
{
  int tg   = blockIdx.x * 256 + threadIdx.x;   // [0, 4*131072)
  int seg  = tg >> 17;
  int s    = tg & 131071;
  int lane = s & 63;
  int ks   = (s >> 6) & 31;
  int mf   = s >> 11;
  int row  = mf * 32 + (lane & 31);
  if (row >= padded[seg]) return;
  int token = lists[seg * 2048 + row];
  unsigned int w[4];
  if (token < NTOK){
    const float* h = hidden + (size_t)token * D + ks * 16 + (lane >> 5) * 8;
    #pragma unroll
    for (int i = 0; i < 4; ++i){
      unsigned short lo = f2bf(h[2*i]);
      unsigned short hi = f2bf(h[2*i+1]);
      w[i] = (unsigned int)lo | ((unsigned int)hi << 16);
    }
  } else {
    w[0] = w[1] = w[2] = w[3] = 0u;
  }
  size_t off = ((size_t)seg * 2048 * 512) + (((size_t)(mf * 32 + ks)) * 64 + lane) * 8;
  uint4 val; val.x = w[0]; val.y = w[1]; val.z = w[2]; val.w = w[3];
  *(uint4*)(frags + off) = val;
}

// ---------------------------------------------------------------------------
// K5: Σexp GEMM. 64-col strips (2 x 32-col chunks), 256 threads, 3 blocks/CU
// (LDS 49 KB). K-loop identical to round-5 (proven VGPR=116, no spill,
// __launch_bounds__(256,2): (256,3) made the allocator spill to chase
// 6 waves/SIMD that LDS can't deliver — WRITE_SIZE 128 MB, round 8).
// Epilogue: round-5 f32 stride-36 transpose-reduce idiom, half-height:
// two 16x36 f32 passes per acc; f32 racc += (wave-owned rows).
// ---------------------------------------------------------------------------
__device__ __forceinline__ void epi(const f32x16& a, float b0v, int r0,
                                    int lane, float* __restrict__ sc_w,
                                    float* __restrict__ racc)
{
  int hi    = lane >> 5;
  int laneM = lane & 31;
  #pragma unroll
  for (int p = 0; p < 2; ++p){
    // write: 8 regs -> 16 rows x 32 cols f32, stride 36 (conflict-free)
    #pragma unroll
    for (int r = 0; r < 8; ++r){
      int row = (r & 3) + 8 * (r >> 2) + 4 * hi;          // 0..15 (local)
      sc_w[row * 36 + laneM] = __expf(a[p * 8 + r] + b0v);
    }
    // read: lane -> row (lane&15), col-quarter (lane>>4); 2x float4
    int rho = lane & 15;
    int q   = lane >> 4;                                  // 0..3
    const float* pr = sc_w + rho * 36 + q * 8;
    float4 v0 = *(const float4*)(pr);
    float4 v1 = *(const float4*)(pr + 4);
    float s = ((v0.x + v0.y) + (v0.z + v0.w)) + ((v1.x + v1.y) + (v1.z + v1.w));
    s += __shfl_xor(s, 16, 64);
    s += __shfl_xor(s, 32, 64);
    if (lane < 16)
      racc[r0 + p * 16 + rho] += s;                       // wave-owned rows
  }
}

__global__ __launch_bounds__(256, 2)
void k_gemm(const unsigned short* __restrict__ frags,
            const float* __restrict__ weight,
            const float* __restrict__ bias,
            const int*   __restrict__ padded,
            unsigned short* __restrict__ partials)   // [1565][2048] bf16
{
  __shared__ unsigned short Bs[512 * 32];      // 32 KB
  __shared__ float sc[4][16 * 36];             // 9 KB (per-wave 16x36 f32)
  __shared__ float racc[2048];                 // 8 KB f32 row accumulator

  int bid = blockIdx.x;
  int seg, strip0, colstart, colend;
  if      (bid < 157) { seg = 0; strip0 = 0;    colstart = 0;     colend = 10000;  }
  else if (bid < 314) { seg = 1; strip0 = 157;  colstart = 10000; colend = 20000;  }
  else if (bid < 783) { seg = 2; strip0 = 314;  colstart = 20000; colend = 50000;  }
  else                { seg = 3; strip0 = 783;  colstart = 50000; colend = 100000; }
  int col_base = colstart + (bid - strip0) * 64;

  int tid   = threadIdx.x;
  int wave  = tid >> 6;
  int lane  = tid & 63;
  int laneM = lane & 31;
  int hi    = lane >> 5;
  int M = padded[seg];
  const unsigned short* fseg = frags + (size_t)seg * 2048 * 512;
  float* sc_w = sc[wave];

  for (int r = tid; r < 2048; r += 256) racc[r] = 0.f;

  const char* bsc = (const char*)Bs;
  int roff = (lane * 16) ^ (hi << 4);   // B read base; (ks&3)<<5 XOR per iter

  for (int chunk = 0; chunk < 2; ++chunk){
    int cb = col_base + chunk * 32;
    // ---- load B chunk: 32 cols x 512 k, f32 -> bf16, frag-native LDS ----
    for (int it = 0; it < 16; ++it){
      int id  = it * 256 + tid;               // [0, 4096)
      int col = id >> 7;                      // 0..31
      int k0  = (id & 127) * 4;               // 0..508
      int cg  = cb + col;
      float4 v = make_float4(0.f, 0.f, 0.f, 0.f);
      if (cg < colend) v = *(const float4*)(weight + (size_t)cg * D + k0);
      unsigned int lo  = (unsigned int)f2bf(v.x) | ((unsigned int)f2bf(v.y) << 16);
      unsigned int hi2 = (unsigned int)f2bf(v.z) | ((unsigned int)f2bf(v.w) << 16);
      int ks = k0 >> 4, bhi = (k0 >> 3) & 1, j0 = k0 & 7;
      int off = ks * 1024 + bhi * 512 + col * 16 + j0 * 2;
      off ^= ((ks & 3) << 5) ^ (bhi << 4);
      uint2 pk; pk.x = lo; pk.y = hi2;
      *(uint2*)((char*)Bs + off) = pk;
    }
    __syncthreads();   // B ready (first pass: racc also zeroed)

    int cg0 = cb + laneM;
    float b0v = (cg0 < colend && !is_root(cg0)) ? bias[cg0] : -INFINITY;

    for (int m0 = 0; m0 < M; m0 += 256){
      int r0 = m0 + wave * 64;
      f32x16 acc0, acc1;
      #pragma unroll
      for (int i = 0; i < 16; ++i){ acc0[i] = 0.f; acc1[i] = 0.f; }

      const unsigned short* pa0 = fseg + (size_t)(r0 >> 5) * 16384 + (size_t)lane * 8;
      const unsigned short* pa1 = pa0 + 16384;

      #pragma unroll
      for (int ks = 0; ks < 32; ++ks){
        bf16x8 a0 = *(const bf16x8*)(pa0 + ks * 512);
        bf16x8 a1 = *(const bf16x8*)(pa1 + ks * 512);
        bf16x8 b0 = *(const bf16x8*)(bsc + (ks * 1024 + (roff ^ ((ks & 3) << 5))));
        acc0 = __builtin_amdgcn_mfma_f32_32x32x16_bf16(a0, b0, acc0, 0, 0, 0);
        acc1 = __builtin_amdgcn_mfma_f32_32x32x16_bf16(a1, b0, acc1, 0, 0, 0);
      }
      epi(acc0, b0v, r0,      lane, sc_w, racc);
      epi(acc1, b0v, r0 + 32, lane, sc_w, racc);
    }
    __syncthreads();   // all waves done with Bs before next chunk overwrites
  }

  // ---- store per-strip partial row sums (coalesced, non-atomic, bf16) ----
  for (int r = tid; r < M; r += 256)
    partials[(size_t)bid * 2048 + r] = f2bf(racc[r]);
}

// ---------------------------------------------------------------------------
// K5b: reduce bf16 partials over strips of each segment, scatter via lists.
// ---------------------------------------------------------------------------
__global__ void k_reduce(const unsigned short* __restrict__ partials,
                         const int*   __restrict__ lists,
                         const int*   __restrict__ padded,
                         float* __restrict__ acc_out)     // [4][2049]
{
  int b   = blockIdx.x;          // 32 blocks: seg = b>>3, row chunk = b&7
  int seg = b >> 3;
  int row = (b & 7) * 256 + threadIdx.x;
  if (row >= padded[seg]) return;
  int base, cnt;
  if      (seg == 0){ base = 0;   cnt = 157; }
  else if (seg == 1){ base = 157; cnt = 157; }
  else if (seg == 2){ base = 314; cnt = 469; }
  else              { base = 783; cnt = 782; }
  float s = 0.f;
  int j = 0;
  for (; j + 4 <= cnt; j += 4){
    s += bf2f(partials[(size_t)(base + j    ) * 2048 + row]);
    s += bf2f(partials[(size_t)(base + j + 1) * 2048 + row]);
    s += bf2f(partials[(size_t)(base + j + 2) * 2048 + row]);
    s += bf2f(partials[(size_t)(base + j + 3) * 2048 + row]);
  }
  for (; j < cnt; ++j) s += bf2f(partials[(size_t)(base + j) * 2048 + row]);
  int token = lists[seg * 2048 + row];
  if (token < NTOK) acc_out[seg * 2049 + token] = s;
}

// ---------------------------------------------------------------------------
// K6: finalize NLL per token.
// ---------------------------------------------------------------------------
__global__ void k_finalize(const float* __restrict__ accs,   // [4][2049]
                           const float* __restrict__ cl,     // [2048][3]
                           const float* __restrict__ tgt,
                           const int*   __restrict__ target,
                           float* __restrict__ out)
{
  int n = blockIdx.x * blockDim.x + threadIdx.x;
  if (n >= NTOK) return;
  int c = cluster_of(target[n]);
  float e0 = __expf(cl[n*3+0]), e1 = __expf(cl[n*3+1]), e2 = __expf(cl[n*3+2]);
  float head_lse = __logf(accs[n] + e0 + e1 + e2);
  float nll;
  if (c == 0){
    nll = head_lse - tgt[n];
  } else {
    float tail_lse = __logf(accs[c * 2049 + n]);
    nll = head_lse + tail_lse - cl[n*3 + (3 - c)] - tgt[n];
  }
  out[n] = nll;
}

extern "C" void kernel_launch(void* const* d_in, const int* in_sizes, int n_in,
                              void* d_out, int out_size, void* d_ws, size_t ws_size,
                              hipStream_t stream)
{
  (void)in_sizes; (void)n_in; (void)out_size; (void)ws_size;
  const float* hidden = (const float*)d_in[0];
  const float* weight = (const float*)d_in[1];
  const float* bias   = (const float*)d_in[2];
  const float* cw     = (const float*)d_in[3];
  const float* cb     = (const float*)d_in[4];
  const int*   target = (const int*)d_in[5];
  float* out = (float*)d_out;
  char*  ws  = (char*)d_ws;

  unsigned short* frags    = (unsigned short*)(ws + WS_FRAGS);
  int*   lists    = (int*)(ws + WS_LISTS);
  unsigned short* partials = (unsigned short*)(ws + WS_PART);
  int*   cursors  = (int*)(ws + WS_CUR);
  int*   padded   = (int*)(ws + WS_PAD);
  float* cl       = (float*)(ws + WS_CL);
  float* tgt      = (float*)(ws + WS_TGT);
  float* acc      = (float*)(ws + WS_ACC);

  hipMemsetAsync(ws + WS_CUR, 0, 16, stream);   // cursors only

  k_token_logits<<<512, 256, 0, stream>>>(hidden, weight, bias, cw, cb, target, cl, tgt);
  k_build_lists <<<8,   256, 0, stream>>>(target, lists, cursors);
  k_pad_lists   <<<1,   256, 0, stream>>>(lists, cursors, padded);
  k_build_frags <<<2048,256, 0, stream>>>(hidden, lists, padded, frags);
  k_gemm        <<<1565,256, 0, stream>>>(frags, weight, bias, padded, partials);
  k_reduce      <<<32,  256, 0, stream>>>(partials, lists, padded, acc);
  k_finalize    <<<8,   256, 0, stream>>>(acc, cl, tgt, target, out);
}

// Round 10
// 310.370 us; speedup vs baseline: 2.0762x; 1.0226x over previous
//
#include <hip/hip_runtime.h>
#include <math.h>

#define NTOK   2048
#define D      512
#define NV     100000

typedef __attribute__((ext_vector_type(8)))  short bf16x8;
typedef __attribute__((ext_vector_type(16))) float f32x16;

// ---- strip geometry: 64 cols/block, 2x 32-col LDS chunks ----
// seg strips: 157, 157, 469, 782  (bases 0, 157, 314, 783; total 1565)

// ---- workspace layout (bytes) ----
#define WS_FRAGS 0u           // 4 segs * 2048 * 512 * 2B = 8,388,608
#define WS_LISTS 8388608u     // 4 * 2048 * 4B = 32,768
#define WS_PART  8421376u     // 1565 * 2048 * 2B (bf16) = 6,410,240 (region 6,422,528)
#define WS_CUR   14843904u    // 16
#define WS_PAD   14843920u    // 16
#define WS_CL    14843936u    // 2048*3*4 = 24,576
#define WS_TGT   14868512u    // 2048*4   = 8,192
#define WS_ACC   14876704u    // 4*2049*4 = 32,784  (end 14,909,488)

__device__ __forceinline__ int cluster_of(int t){
  return (t < 10000) ? 0 : (t < 20000) ? 1 : (t < 50000) ? 2 : 3;
}
__device__ __forceinline__ bool is_root(int c){
  return c==5 || c==17 || c==123 || c==10005 || c==20007 || c==50011;
}
// f32 -> bf16 round-to-nearest-even
__device__ __forceinline__ unsigned short f2bf(float f){
  unsigned int u = __float_as_uint(f);
  u += 0x7fffu + ((u >> 16) & 1u);
  return (unsigned short)(u >> 16);
}
__device__ __forceinline__ float bf2f(unsigned short u){
  unsigned int v = ((unsigned int)u) << 16;
  return __uint_as_float(v);
}

// ---------------------------------------------------------------------------
// K1: per-token cluster logits (3 dots) + exact-f32 target logit. 1 wave/token.
// ---------------------------------------------------------------------------
__global__ void k_token_logits(const float* __restrict__ hidden,
                               const float* __restrict__ weight,
                               const float* __restrict__ bias,
                               const float* __restrict__ cw,
                               const float* __restrict__ cb,
                               const int*   __restrict__ target,
                               float* __restrict__ cl_out,   // [2048][3]
                               float* __restrict__ tgt_out)  // [2048]
{
  int wave = threadIdx.x >> 6;
  int lane = threadIdx.x & 63;
  int n = blockIdx.x * 4 + wave;
  if (n >= NTOK) return;
  const float* h = hidden + (size_t)n * D + lane * 8;
  int t = target[n];
  const float* wt = weight + (size_t)t * D + lane * 8;
  float hv[8];
  #pragma unroll
  for (int i = 0; i < 8; ++i) hv[i] = h[i];
  float acc[4] = {0.f, 0.f, 0.f, 0.f};
  #pragma unroll
  for (int j = 0; j < 3; ++j){
    const float* cwj = cw + j * D + lane * 8;
    float s = 0.f;
    #pragma unroll
    for (int i = 0; i < 8; ++i) s += hv[i] * cwj[i];
    acc[j] = s;
  }
  {
    float s = 0.f;
    #pragma unroll
    for (int i = 0; i < 8; ++i) s += hv[i] * wt[i];
    acc[3] = s;
  }
  #pragma unroll
  for (int m = 1; m < 64; m <<= 1){
    #pragma unroll
    for (int j = 0; j < 4; ++j) acc[j] += __shfl_xor(acc[j], m, 64);
  }
  if (lane == 0){
    cl_out[n*3+0] = acc[0] + cb[0];
    cl_out[n*3+1] = acc[1] + cb[1];
    cl_out[n*3+2] = acc[2] + cb[2];
    float tg = acc[3] + bias[t];
    if (is_root(t)) tg = -INFINITY;
    tgt_out[n] = tg;
  }
}

// ---------------------------------------------------------------------------
// K2: build per-segment token lists. seg0 = identity; tails via atomic cursor.
// ---------------------------------------------------------------------------
__global__ void k_build_lists(const int* __restrict__ target,
                              int* __restrict__ lists, int* __restrict__ cursors)
{
  int n = blockIdx.x * blockDim.x + threadIdx.x;
  if (n >= NTOK) return;
  lists[n] = n;  // seg 0 identity
  int c = cluster_of(target[n]);
  if (c > 0){
    int pos = atomicAdd(cursors + c, 1);
    lists[c * 2048 + pos] = n;
  }
}

// ---------------------------------------------------------------------------
// K3: pad lists to multiples of 256 with sentinel token (=NTOK), write counts.
// ---------------------------------------------------------------------------
__global__ void k_pad_lists(int* __restrict__ lists, const int* __restrict__ cursors,
                            int* __restrict__ padded)
{
  if (threadIdx.x == 0) padded[0] = NTOK;
  for (int s = 1; s < 4; ++s){
    int c = cursors[s];
    int p = (c + 255) & ~255;
    if (threadIdx.x == 0) padded[s] = p;
    for (int i = c + threadIdx.x; i < p; i += blockDim.x)
      lists[s * 2048 + i] = NTOK;
  }
}

// ---------------------------------------------------------------------------
// K4: build bf16 A-fragments in MFMA-native layout per segment.
// elem offset = ((mf*32 + ks)*64 + lane)*8 ; row = mf*32+(lane&31),
// k = ks*16 + (lane>>5)*8 + j  (same k-convention as B).
// ---------------------------------------------------------------------------
__global__ void k_build_frags(const float* __restrict__ hidden,
                              const int*   __restrict__ lists,
                              const int*   __restrict__ padded,
                              unsigned short* __restrict__ frags)
{
  int tg   = blockIdx.x * 256 + threadIdx.x;   // [0, 4*131072)
  int seg  = tg >> 17;
  int s    = tg & 131071;
  int lane = s & 63;
  int ks   = (s >> 6) & 31;
  int mf   = s >> 11;
  int row  = mf * 32 + (lane & 31);
  if (row >= padded[seg]) return;
  int token = lists[seg * 2048 + row];
  unsigned int w[4];
  if (token < NTOK){
    const float* h = hidden + (size_t)token * D + ks * 16 + (lane >> 5) * 8;
    #pragma unroll
    for (int i = 0; i < 4; ++i){
      unsigned short lo = f2bf(h[2*i]);
      unsigned short hi = f2bf(h[2*i+1]);
      w[i] = (unsigned int)lo | ((unsigned int)hi << 16);
    }
  } else {
    w[0] = w[1] = w[2] = w[3] = 0u;
  }
  size_t off = ((size_t)seg * 2048 * 512) + (((size_t)(mf * 32 + ks)) * 64 + lane) * 8;
  uint4 val; val.x = w[0]; val.y = w[1]; val.z = w[2]; val.w = w[3];
  *(uint4*)(frags + off) = val;
}

// ---------------------------------------------------------------------------
// K5: Σexp GEMM. 64-col strips (2 x 32-col chunks), 256 threads, 4 blocks/CU
// (LDS exactly 40 KB = 32 KB Bs + 8 KB racc). K-loop verbatim from round 5/9
// (VGPR=124, no spill, __launch_bounds__(256,2) — (256,3+) makes the
// allocator spill-chase; round 8 lesson). Epilogue: round-6 in-register
// halving-tree reduce (HW-verified numerics), no LDS scratch.
// ---------------------------------------------------------------------------
__device__ __forceinline__ void epi(const f32x16& a, float b0v, int r0,
                                    int lane, float* __restrict__ racc)
{
  float v[16];
  #pragma unroll
  for (int r = 0; r < 16; ++r) v[r] = __expf(a[r] + b0v);
  // halving tree over the 16 low lane-bits: 15+ shuffles, 16 regs -> 1
  #pragma unroll
  for (int lvl = 0; lvl < 4; ++lvl){
    int m = 1 << lvl;
    int half = 8 >> lvl;
    bool up = (lane & m) != 0;
    #pragma unroll
    for (int i = 0; i < half; ++i){
      float lo = v[i], hi_ = v[i + half];
      float other = __shfl_xor(up ? lo : hi_, m, 64);
      v[i] = (up ? hi_ : lo) + other;
    }
  }
  float s = v[0] + __shfl_xor(v[0], 16, 64);   // last col-reduction level
  if ((lane & 16) == 0){
    int l  = lane & 15;
    int rl = ((l & 1) << 3) | ((l & 2) << 1) | ((l & 4) >> 1) | ((l & 8) >> 3);
    int row = (rl & 3) + 8 * (rl >> 2) + 4 * (lane >> 5);  // verified C/D layout
    racc[r0 + row] += s;   // 32 active lanes -> 32 distinct wave-owned rows
  }
}

__global__ __launch_bounds__(256, 2)
void k_gemm(const unsigned short* __restrict__ frags,
            const float* __restrict__ weight,
            const float* __restrict__ bias,
            const int*   __restrict__ padded,
            unsigned short* __restrict__ partials)   // [1565][2048] bf16
{
  __shared__ unsigned short Bs[512 * 32];      // 32 KB
  __shared__ float racc[2048];                 // 8 KB f32 row accumulator

  int bid = blockIdx.x;
  int seg, strip0, colstart, colend;
  if      (bid < 157) { seg = 0; strip0 = 0;    colstart = 0;     colend = 10000;  }
  else if (bid < 314) { seg = 1; strip0 = 157;  colstart = 10000; colend = 20000;  }
  else if (bid < 783) { seg = 2; strip0 = 314;  colstart = 20000; colend = 50000;  }
  else                { seg = 3; strip0 = 783;  colstart = 50000; colend = 100000; }
  int col_base = colstart + (bid - strip0) * 64;

  int tid   = threadIdx.x;
  int wave  = tid >> 6;
  int lane  = tid & 63;
  int laneM = lane & 31;
  int hi    = lane >> 5;
  int M = padded[seg];
  const unsigned short* fseg = frags + (size_t)seg * 2048 * 512;

  for (int r = tid; r < 2048; r += 256) racc[r] = 0.f;

  const char* bsc = (const char*)Bs;
  int roff = (lane * 16) ^ (hi << 4);   // B read base; (ks&3)<<5 XOR per iter

  for (int chunk = 0; chunk < 2; ++chunk){
    int cb = col_base + chunk * 32;
    // ---- load B chunk: 32 cols x 512 k, f32 -> bf16, frag-native LDS ----
    for (int it = 0; it < 16; ++it){
      int id  = it * 256 + tid;               // [0, 4096)
      int col = id >> 7;                      // 0..31
      int k0  = (id & 127) * 4;               // 0..508
      int cg  = cb + col;
      float4 v = make_float4(0.f, 0.f, 0.f, 0.f);
      if (cg < colend) v = *(const float4*)(weight + (size_t)cg * D + k0);
      unsigned int lo  = (unsigned int)f2bf(v.x) | ((unsigned int)f2bf(v.y) << 16);
      unsigned int hi2 = (unsigned int)f2bf(v.z) | ((unsigned int)f2bf(v.w) << 16);
      int ks = k0 >> 4, bhi = (k0 >> 3) & 1, j0 = k0 & 7;
      int off = ks * 1024 + bhi * 512 + col * 16 + j0 * 2;
      off ^= ((ks & 3) << 5) ^ (bhi << 4);
      uint2 pk; pk.x = lo; pk.y = hi2;
      *(uint2*)((char*)Bs + off) = pk;
    }
    __syncthreads();   // B ready (first pass: racc also zeroed)

    int cg0 = cb + laneM;
    float b0v = (cg0 < colend && !is_root(cg0)) ? bias[cg0] : -INFINITY;

    for (int m0 = 0; m0 < M; m0 += 256){
      int r0 = m0 + wave * 64;
      f32x16 acc0, acc1;
      #pragma unroll
      for (int i = 0; i < 16; ++i){ acc0[i] = 0.f; acc1[i] = 0.f; }

      const unsigned short* pa0 = fseg + (size_t)(r0 >> 5) * 16384 + (size_t)lane * 8;
      const unsigned short* pa1 = pa0 + 16384;

      #pragma unroll
      for (int ks = 0; ks < 32; ++ks){
        bf16x8 a0 = *(const bf16x8*)(pa0 + ks * 512);
        bf16x8 a1 = *(const bf16x8*)(pa1 + ks * 512);
        bf16x8 b0 = *(const bf16x8*)(bsc + (ks * 1024 + (roff ^ ((ks & 3) << 5))));
        acc0 = __builtin_amdgcn_mfma_f32_32x32x16_bf16(a0, b0, acc0, 0, 0, 0);
        acc1 = __builtin_amdgcn_mfma_f32_32x32x16_bf16(a1, b0, acc1, 0, 0, 0);
      }
      epi(acc0, b0v, r0,      lane, racc);
      epi(acc1, b0v, r0 + 32, lane, racc);
    }
    __syncthreads();   // all waves done with Bs before next chunk overwrites
  }

  // ---- store per-strip partial row sums (coalesced, non-atomic, bf16) ----
  for (int r = tid; r < M; r += 256)
    partials[(size_t)bid * 2048 + r] = f2bf(racc[r]);
}

// ---------------------------------------------------------------------------
// K5b: reduce bf16 partials over strips of each segment, scatter via lists.
// ---------------------------------------------------------------------------
__global__ void k_reduce(const unsigned short* __restrict__ partials,
                         const int*   __restrict__ lists,
                         const int*   __restrict__ padded,
                         float* __restrict__ acc_out)     // [4][2049]
{
  int b   = blockIdx.x;          // 32 blocks: seg = b>>3, row chunk = b&7
  int seg = b >> 3;
  int row = (b & 7) * 256 + threadIdx.x;
  if (row >= padded[seg]) return;
  int base, cnt;
  if      (seg == 0){ base = 0;   cnt = 157; }
  else if (seg == 1){ base = 157; cnt = 157; }
  else if (seg == 2){ base = 314; cnt = 469; }
  else              { base = 783; cnt = 782; }
  float s = 0.f;
  int j = 0;
  for (; j + 4 <= cnt; j += 4){
    s += bf2f(partials[(size_t)(base + j    ) * 2048 + row]);
    s += bf2f(partials[(size_t)(base + j + 1) * 2048 + row]);
    s += bf2f(partials[(size_t)(base + j + 2) * 2048 + row]);
    s += bf2f(partials[(size_t)(base + j + 3) * 2048 + row]);
  }
  for (; j < cnt; ++j) s += bf2f(partials[(size_t)(base + j) * 2048 + row]);
  int token = lists[seg * 2048 + row];
  if (token < NTOK) acc_out[seg * 2049 + token] = s;
}

// ---------------------------------------------------------------------------
// K6: finalize NLL per token.
// ---------------------------------------------------------------------------
__global__ void k_finalize(const float* __restrict__ accs,   // [4][2049]
                           const float* __restrict__ cl,     // [2048][3]
                           const float* __restrict__ tgt,
                           const int*   __restrict__ target,
                           float* __restrict__ out)
{
  int n = blockIdx.x * blockDim.x + threadIdx.x;
  if (n >= NTOK) return;
  int c = cluster_of(target[n]);
  float e0 = __expf(cl[n*3+0]), e1 = __expf(cl[n*3+1]), e2 = __expf(cl[n*3+2]);
  float head_lse = __logf(accs[n] + e0 + e1 + e2);
  float nll;
  if (c == 0){
    nll = head_lse - tgt[n];
  } else {
    float tail_lse = __logf(accs[c * 2049 + n]);
    nll = head_lse + tail_lse - cl[n*3 + (3 - c)] - tgt[n];
  }
  out[n] = nll;
}

extern "C" void kernel_launch(void* const* d_in, const int* in_sizes, int n_in,
                              void* d_out, int out_size, void* d_ws, size_t ws_size,
                              hipStream_t stream)
{
  (void)in_sizes; (void)n_in; (void)out_size; (void)ws_size;
  const float* hidden = (const float*)d_in[0];
  const float* weight = (const float*)d_in[1];
  const float* bias   = (const float*)d_in[2];
  const float* cw     = (const float*)d_in[3];
  const float* cb     = (const float*)d_in[4];
  const int*   target = (const int*)d_in[5];
  float* out = (float*)d_out;
  char*  ws  = (char*)d_ws;

  unsigned short* frags    = (unsigned short*)(ws + WS_FRAGS);
  int*   lists    = (int*)(ws + WS_LISTS);
  unsigned short* partials = (unsigned short*)(ws + WS_PART);
  int*   cursors  = (int*)(ws + WS_CUR);
  int*   padded   = (int*)(ws + WS_PAD);
  float* cl       = (float*)(ws + WS_CL);
  float* tgt      = (float*)(ws + WS_TGT);
  float* acc      = (float*)(ws + WS_ACC);

  hipMemsetAsync(ws + WS_CUR, 0, 16, stream);   // cursors only

  k_token_logits<<<512, 256, 0, stream>>>(hidden, weight, bias, cw, cb, target, cl, tgt);
  k_build_lists <<<8,   256, 0, stream>>>(target, lists, cursors);
  k_pad_lists   <<<1,   256, 0, stream>>>(lists, cursors, padded);
  k_build_frags <<<2048,256, 0, stream>>>(hidden, lists, padded, frags);
  k_gemm        <<<1565,256, 0, stream>>>(frags, weight, bias, padded, partials);
  k_reduce      <<<32,  256, 0, stream>>>(partials, lists, padded, acc);
  k_finalize    <<<8,   256, 0, stream>>>(acc, cl, tgt, target, out);
}